// Round 1
// baseline (843.150 us; speedup 1.0000x reference)
//
#include <hip/hip_runtime.h>

// SelfAttention: B=4, L=4096, H=256, fp32 in/out.
// Pipeline:
//   k1 wsplit:   W[3][256][256] fp32 -> Wht/Wlt [3][n][h] bf16 hi/lo (transposed for B-frags)
//   k2 qkv_proj: X fp32 -> Qh/Ql (pre-scaled by log2e/16), Kh/Kl (natural [tok][d]),
//                Vt (plain bf16, transposed [b][d][tok])
//   k3 attn:     flash attention, 1 block per 64 q-rows, 32-key tiles,
//                split-bf16 3-product QK^T (fp32-accurate logits), plain-bf16 PV.
// Precision rationale: logits reach O(1e4) with rare near-tie top-2 gaps ~1;
// plain bf16 QK (logit err ~0.7) would blow the 1.01 absmax threshold on
// near-tie rows. Split-bf16 3-product gives logit err ~1e-3.

typedef __bf16 bf16x8 __attribute__((ext_vector_type(8)));
typedef __bf16 bf16x4 __attribute__((ext_vector_type(4)));
typedef float floatx4 __attribute__((ext_vector_type(4)));

#define MFMA16(a, b, c) __builtin_amdgcn_mfma_f32_16x16x32_bf16(a, b, c, 0, 0, 0)

#define HID 256
#define LSEQ 4096
#define NB 4
#define NTOK (NB * LSEQ)           // 16384
#define QSCALE 0.09016844005556021f  // log2(e)/16 ; folded into Q so softmax uses exp2

__device__ __forceinline__ void split_bf16(float v, __bf16 &h, __bf16 &l) {
  h = (__bf16)v;
  l = (__bf16)(v - (float)h);
}

// ---------------------------------------------------------------------------
// Kernel 1: transpose + hi/lo-split the three weight matrices.
// Output: Wht/Wlt[w][n][h] (n-major) so GEMM B-fragments are 16B-contiguous.
// grid = 3 blocks x 256 threads. Tiny (0.4 MB), LDS tile transpose for coalescing.
// ---------------------------------------------------------------------------
__global__ __launch_bounds__(256) void wsplit(const float *__restrict__ Wq,
                                              const float *__restrict__ Wk,
                                              const float *__restrict__ Wv,
                                              __bf16 *__restrict__ Wht,
                                              __bf16 *__restrict__ Wlt) {
  __shared__ float tile[32][256];  // 32 KB
  const int wsel = blockIdx.x;
  const float *W = (wsel == 0) ? Wq : (wsel == 1) ? Wk : Wv;
  __bf16 *oh = Wht + wsel * HID * HID;
  __bf16 *ol = Wlt + wsel * HID * HID;
  const int t = threadIdx.x;
  for (int hb = 0; hb < 8; ++hb) {  // 32 h-rows per pass
    __syncthreads();                 // protect previous tile reads
    #pragma unroll
    for (int p = 0; p < 8; ++p) {    // load 32x256 fp32, coalesced
      int r = p * 4 + (t >> 6);
      int c = (t & 63) * 4;
      *(floatx4 *)&tile[r][c] = *(const floatx4 *)&W[(hb * 32 + r) * HID + c];
    }
    __syncthreads();
    #pragma unroll
    for (int q = 0; q < 4; ++q) {    // write transposed: thread -> (n = q*64+t/4, 8 h's)
      int n = q * 64 + (t >> 2);
      int hs = (t & 3) * 8;
      bf16x8 hh, ll;
      #pragma unroll
      for (int i = 0; i < 8; ++i) {
        float v = tile[hs + i][n];
        __bf16 h, l;
        split_bf16(v, h, l);
        hh[i] = h; ll[i] = l;
      }
      *(bf16x8 *)&oh[n * HID + hb * 32 + hs] = hh;
      *(bf16x8 *)&ol[n * HID + hb * 32 + hs] = ll;
    }
  }
}

// ---------------------------------------------------------------------------
// Kernel 2: QKV projection, LDS-free MFMA GEMM.
// grid = (256 m-tiles of 64 tokens, 12 n-tiles: [0..3]=Q [4..7]=K [8..11]=V).
// A-frags: X fp32 from global, hi/lo split in registers.
// B-frags: 16B loads from global Wht/Wlt (L2-hot, reused by all 256 m-tiles).
// 3-product split GEMM -> fp32 acc. Q scaled by log2e/16 then hi/lo stored;
// K hi/lo stored; V stored plain bf16 TRANSPOSED (C-layout gives contiguous
// 4-token column segments -> single 8 B stores).
// ---------------------------------------------------------------------------
__global__ __launch_bounds__(256) void qkv_proj(const float *__restrict__ X,
                                                const __bf16 *__restrict__ Wht,
                                                const __bf16 *__restrict__ Wlt,
                                                __bf16 *__restrict__ Qh, __bf16 *__restrict__ Ql,
                                                __bf16 *__restrict__ Kh, __bf16 *__restrict__ Kl,
                                                __bf16 *__restrict__ Vt) {
  const int mtile = blockIdx.x;        // 0..255
  const int nb = blockIdx.y;           // 0..11
  const int w = nb >> 2;               // 0=Q 1=K 2=V
  const int col0 = (nb & 3) * 64;
  const int tid = threadIdx.x;
  const int w4 = tid >> 6;
  const int lane = tid & 63;
  const int quad = lane >> 4;
  const int ln = lane & 15;
  const __bf16 *wh = Wht + w * HID * HID;
  const __bf16 *wl = Wlt + w * HID * HID;
  const int arow = mtile * 64 + w4 * 16 + ln;  // token row for A-frags

  floatx4 acc[4] = {};
  #pragma unroll
  for (int kc = 0; kc < 8; ++kc) {
    const int koff = kc * 32 + quad * 8;
    const float *xp = X + arow * HID + koff;
    floatx4 x0 = *(const floatx4 *)xp;
    floatx4 x1 = *(const floatx4 *)(xp + 4);
    bf16x8 ah, al;
    #pragma unroll
    for (int j = 0; j < 4; ++j) {
      __bf16 h, l;
      split_bf16(x0[j], h, l); ah[j] = h; al[j] = l;
      split_bf16(x1[j], h, l); ah[4 + j] = h; al[4 + j] = l;
    }
    #pragma unroll
    for (int nt = 0; nt < 4; ++nt) {
      const int woff = (col0 + nt * 16 + ln) * HID + koff;
      bf16x8 bh = *(const bf16x8 *)&wh[woff];
      bf16x8 bl = *(const bf16x8 *)&wl[woff];
      acc[nt] = MFMA16(ah, bh, acc[nt]);
      acc[nt] = MFMA16(ah, bl, acc[nt]);
      acc[nt] = MFMA16(al, bh, acc[nt]);
    }
  }

  // Epilogue. C/D layout: col = lane&15, row = quad*4 + reg (HW-verified).
  if (w == 2) {
    const int bb = mtile >> 6;                         // batch
    const int l0 = (mtile & 63) * 64 + w4 * 16 + quad * 4;  // token within batch
    #pragma unroll
    for (int nt = 0; nt < 4; ++nt) {
      const int d = col0 + nt * 16 + ln;
      bf16x4 pk;
      #pragma unroll
      for (int r = 0; r < 4; ++r) pk[r] = (__bf16)acc[nt][r];
      *(bf16x4 *)&Vt[(size_t)(bb * HID + d) * LSEQ + l0] = pk;
    }
  } else {
    __bf16 *H = (w == 0) ? Qh : Kh;
    __bf16 *L = (w == 0) ? Ql : Kl;
    const float sc = (w == 0) ? QSCALE : 1.0f;
    #pragma unroll
    for (int nt = 0; nt < 4; ++nt) {
      #pragma unroll
      for (int r = 0; r < 4; ++r) {
        float v = acc[nt][r] * sc;
        __bf16 h, l;
        split_bf16(v, h, l);
        const int orow = mtile * 64 + w4 * 16 + quad * 4 + r;
        const int ocol = col0 + nt * 16 + ln;
        H[orow * HID + ocol] = h;
        L[orow * HID + ocol] = l;
      }
    }
  }
}

// ---------------------------------------------------------------------------
// Kernel 3: flash attention. grid = 256 blocks (b = bx>>6, qtile = bx&63),
// 256 threads = 4 waves, each wave owns 16 q-rows. 32-key tiles, 128 iters.
// LDS (59.4 KB static, <64 KB cap):
//   KhS/KlS [32][264]  : K hi/lo, +8 pad -> 2-way-free b128 frag reads
//   VtS     [256][40]  : V^T tile, 16B-chunk xor swizzle (c ^ (d&3)) for banks
//   PsS     [64][40]   : P round-trip C-layout -> A-layout
// Q hi/lo frags live in registers (64 VGPRs); occupancy 1 block/CU so the
// 512-VGPR budget applies.
// ---------------------------------------------------------------------------
__global__ __launch_bounds__(256, 1) void attn(const __bf16 *__restrict__ QhG,
                                               const __bf16 *__restrict__ QlG,
                                               const __bf16 *__restrict__ KhG,
                                               const __bf16 *__restrict__ KlG,
                                               const __bf16 *__restrict__ VtG,
                                               float *__restrict__ Out) {
  __shared__ __bf16 KhS[32 * 264];
  __shared__ __bf16 KlS[32 * 264];
  __shared__ __bf16 VtS[256 * 40];
  __shared__ __bf16 PsS[64 * 40];

  const int bx = blockIdx.x;
  const int b = bx >> 6;
  const int qt = bx & 63;
  const int tid = threadIdx.x;
  const int w4 = tid >> 6;
  const int lane = tid & 63;
  const int quad = lane >> 4;
  const int ln = lane & 15;

  // Preload Q fragments (hi+lo) for this wave's 16 q-rows.
  const int qtok = b * LSEQ + qt * 64 + w4 * 16 + ln;
  bf16x8 qh[8], ql[8];
  #pragma unroll
  for (int kc = 0; kc < 8; ++kc) {
    const int off = qtok * HID + kc * 32 + quad * 8;
    qh[kc] = *(const bf16x8 *)&QhG[off];
    ql[kc] = *(const bf16x8 *)&QlG[off];
  }

  float m[4] = {-1e30f, -1e30f, -1e30f, -1e30f};
  float l[4] = {0.f, 0.f, 0.f, 0.f};
  floatx4 o[16] = {};

  for (int kt = 0; kt < 128; ++kt) {
    __syncthreads();  // previous iteration's LDS reads complete
    // ---- stage K hi/lo tile [32][256] ----
    #pragma unroll
    for (int p = 0; p < 4; ++p) {
      const int key = p * 8 + (tid >> 5);
      const int c = (tid & 31) * 8;
      const int g = (b * LSEQ + kt * 32 + key) * HID + c;
      *(bf16x8 *)&KhS[key * 264 + c] = *(const bf16x8 *)&KhG[g];
      *(bf16x8 *)&KlS[key * 264 + c] = *(const bf16x8 *)&KlG[g];
    }
    // ---- stage V^T tile [256 d][32 keys], swizzled 16B chunks ----
    {
      const __bf16 *vg = VtG + (size_t)(b * HID + tid) * LSEQ + kt * 32;
      const int s = tid & 3;
      #pragma unroll
      for (int c = 0; c < 4; ++c)
        *(bf16x8 *)&VtS[tid * 40 + ((c ^ s) << 3)] = *(const bf16x8 *)&vg[c << 3];
    }
    __syncthreads();

    // ---- S = Q K^T (3-product split), fp32 acc ----
    floatx4 s[2] = {};
    #pragma unroll
    for (int nt = 0; nt < 2; ++nt) {
      #pragma unroll
      for (int kc = 0; kc < 8; ++kc) {
        const int a = (nt * 16 + ln) * 264 + kc * 32 + quad * 8;
        bf16x8 bh = *(const bf16x8 *)&KhS[a];
        bf16x8 bl = *(const bf16x8 *)&KlS[a];
        s[nt] = MFMA16(qh[kc], bh, s[nt]);
        s[nt] = MFMA16(qh[kc], bl, s[nt]);
        s[nt] = MFMA16(ql[kc], bh, s[nt]);
      }
    }

    // ---- online softmax (base-2; log2e folded into Q) ----
    float alpha[4];
    #pragma unroll
    for (int r = 0; r < 4; ++r) {
      float tmax = fmaxf(s[0][r], s[1][r]);
      #pragma unroll
      for (int d = 1; d < 16; d <<= 1) tmax = fmaxf(tmax, __shfl_xor(tmax, d));
      const float mn = fmaxf(m[r], tmax);
      const float al = exp2f(m[r] - mn);
      const float p0 = exp2f(s[0][r] - mn);
      const float p1 = exp2f(s[1][r] - mn);
      s[0][r] = p0; s[1][r] = p1;
      float rs = p0 + p1;
      #pragma unroll
      for (int d = 1; d < 16; d <<= 1) rs += __shfl_xor(rs, d);
      l[r] = l[r] * al + rs;
      m[r] = mn;
      alpha[r] = al;
    }
    #pragma unroll
    for (int dt = 0; dt < 16; ++dt) {
      o[dt][0] *= alpha[0]; o[dt][1] *= alpha[1];
      o[dt][2] *= alpha[2]; o[dt][3] *= alpha[3];
    }

    // ---- P: C-layout regs -> LDS (row = quad*4+reg, col = nt*16+ln) ----
    #pragma unroll
    for (int nt = 0; nt < 2; ++nt)
      #pragma unroll
      for (int r = 0; r < 4; ++r)
        PsS[(w4 * 16 + quad * 4 + r) * 40 + nt * 16 + ln] = (__bf16)s[nt][r];
    __syncthreads();

    // ---- O += P V : A-frag from PsS, B-frag from swizzled VtS ----
    const bf16x8 pa = *(const bf16x8 *)&PsS[(w4 * 16 + ln) * 40 + quad * 8];
    #pragma unroll
    for (int dt = 0; dt < 16; ++dt) {
      const int d = dt * 16 + ln;
      const int cs = (quad ^ (ln & 3)) << 3;
      bf16x8 vb = *(const bf16x8 *)&VtS[d * 40 + cs];
      o[dt] = MFMA16(pa, vb, o[dt]);
    }
  }

  // ---- epilogue: O / l, fp32 stores ----
  float rl[4];
  #pragma unroll
  for (int r = 0; r < 4; ++r) rl[r] = 1.0f / l[r];
  #pragma unroll
  for (int dt = 0; dt < 16; ++dt) {
    #pragma unroll
    for (int r = 0; r < 4; ++r) {
      const int row = b * LSEQ + qt * 64 + w4 * 16 + quad * 4 + r;
      Out[(size_t)row * HID + dt * 16 + ln] = o[dt][r] * rl[r];
    }
  }
}

// ---------------------------------------------------------------------------
extern "C" void kernel_launch(void *const *d_in, const int *in_sizes, int n_in,
                              void *d_out, int out_size, void *d_ws, size_t ws_size,
                              hipStream_t stream) {
  const float *X = (const float *)d_in[0];
  const float *Wq = (const float *)d_in[1];
  const float *Wk = (const float *)d_in[2];
  const float *Wv = (const float *)d_in[3];
  // d_in[4] = lengths (unused by reference)

  // Workspace layout (bf16 elements). Total ~42.7 MB.
  __bf16 *ws = (__bf16 *)d_ws;
  const size_t PLANE = (size_t)NTOK * HID;  // 4,194,304 elements
  __bf16 *Qh = ws;
  __bf16 *Ql = Qh + PLANE;
  __bf16 *Kh = Ql + PLANE;
  __bf16 *Kl = Kh + PLANE;
  __bf16 *Vt = Kl + PLANE;                   // [B][256][4096]
  __bf16 *Wht = Vt + PLANE;                  // [3][256][256]
  __bf16 *Wlt = Wht + 3 * HID * HID;

  wsplit<<<3, 256, 0, stream>>>(Wq, Wk, Wv, Wht, Wlt);
  qkv_proj<<<dim3(256, 12), 256, 0, stream>>>(X, Wht, Wlt, Qh, Ql, Kh, Kl, Vt);
  attn<<<256, 256, 0, stream>>>(Qh, Ql, Kh, Kl, Vt, (float *)d_out);
}